// Round 1
// baseline (353.588 us; speedup 1.0000x reference)
//
#include <hip/hip_runtime.h>
#include <stdint.h>

#define NROWS 16384
#define DIM 512
#define CSPLIT 8
#define COLS_PER_SPLIT (NROWS / CSPLIT)   // 2048
#define BM 64
#define NT 64
#define BK 64
#define NTILES (COLS_PER_SPLIT / NT)      // 32
#define NPHASE (NTILES * 8)               // 256

using short8 = __attribute__((ext_vector_type(8))) short;
using f32x4  = __attribute__((ext_vector_type(4))) float;

#define AS1 __attribute__((address_space(1)))
#define AS3 __attribute__((address_space(3)))

__device__ __forceinline__ unsigned short f2bf(float f) {
  uint32_t u = __float_as_uint(f);
  u += 0x7FFFu + ((u >> 16) & 1u);   // round-to-nearest-even
  return (unsigned short)(u >> 16);
}

// ---------------- Kernel A: row L2-normalize, write bf16 copy + inv-norm ----
__global__ __launch_bounds__(256) void knorm(const float* __restrict__ in,
                                             unsigned short* __restrict__ xb,
                                             float* __restrict__ inv) {
  const int lane = threadIdx.x & 63;
  const int wave = threadIdx.x >> 6;
  const int row = blockIdx.x * 4 + wave;
  const float4* p = (const float4*)(in + (size_t)row * DIM + lane * 8);
  float4 a = p[0], b = p[1];
  float ss = a.x*a.x + a.y*a.y + a.z*a.z + a.w*a.w
           + b.x*b.x + b.y*b.y + b.z*b.z + b.w*b.w;
  #pragma unroll
  for (int m = 32; m >= 1; m >>= 1) ss += __shfl_xor(ss, m, 64);
  const float iv = 1.0f / fmaxf(sqrtf(ss), 1e-8f);
  short8 ov;
  ov[0] = (short)f2bf(a.x * iv); ov[1] = (short)f2bf(a.y * iv);
  ov[2] = (short)f2bf(a.z * iv); ov[3] = (short)f2bf(a.w * iv);
  ov[4] = (short)f2bf(b.x * iv); ov[5] = (short)f2bf(b.y * iv);
  ov[6] = (short)f2bf(b.z * iv); ov[7] = (short)f2bf(b.w * iv);
  *(short8*)(xb + (size_t)row * DIM + lane * 8) = ov;
  if (lane == 0) inv[row] = iv;
}

// ---------------- Kernel B: Gram matrix (x x^T) + fused running argmax ------
// Grid: (NROWS/BM) * CSPLIT blocks of 256 threads (4 waves x 16 rows each).
// A (16 rows x 512) lives in registers per wave. B column tiles (64 cols x
// 64 k) double-buffered in LDS via global_load_lds(16B) with XOR-swizzled
// global source so ds_read_b128 fragment reads are conflict-free.
__global__ __launch_bounds__(256) void kdots(const unsigned short* __restrict__ xb,
                                             float* __restrict__ pmax,
                                             int* __restrict__ pidx) {
  const int tid  = threadIdx.x;
  const int lane = tid & 63;
  const int wave = tid >> 6;
  const int bx = blockIdx.x;
  const int cs = bx & (CSPLIT - 1);     // same-cs blocks land on same XCD (%8)
  const int rb = bx >> 3;
  const int rowbase  = rb * BM + wave * 16;
  const int colsplit = cs * COLS_PER_SPLIT;

  __shared__ unsigned short lds[2][NT * BK];   // 2 x 8 KB

  // ---- A fragments in registers: 16 rows x 512 (64 VGPRs) ----
  short8 areg[16];
  {
    const unsigned short* ap =
        xb + (size_t)(rowbase + (lane & 15)) * DIM + ((lane >> 4) * 8);
    #pragma unroll
    for (int c = 0; c < 16; ++c)
      areg[c] = *(const short8*)(ap + c * 32);
  }

  float rmax[4] = {-3e38f, -3e38f, -3e38f, -3e38f};
  int   ridx[4] = {0, 0, 0, 0};

  auto STAGE = [&](int buf, int u) {
    const int t = u >> 3, kb = u & 7;
    const int colbase = colsplit + t * NT;
    #pragma unroll
    for (int i = 0; i < 2; ++i) {
      const int d = i * 4096 + tid * 16;          // linear dest byte in buffer
      const int col = d >> 7;                     // 128 B per column (64 bf16)
      const int kel = ((tid & 7) ^ (col & 7)) * 8; // pre-swizzled global source
      const unsigned short* g =
          xb + (size_t)(colbase + col) * DIM + kb * BK + kel;
      char* lbase = ((char*)&lds[buf][0]) + i * 4096 + wave * 1024;
      __builtin_amdgcn_global_load_lds((AS1 const void*)g, (AS3 void*)lbase,
                                       16, 0, 0);
    }
  };

  STAGE(0, 0);
  int cur = 0;
  for (int t = 0; t < NTILES; ++t) {
    f32x4 acc[4] = {{0,0,0,0},{0,0,0,0},{0,0,0,0},{0,0,0,0}};
    #pragma unroll
    for (int kb = 0; kb < 8; ++kb) {
      const int u = t * 8 + kb;
      __syncthreads();                       // buf[cur] staged; buf[cur^1] free
      if (u + 1 < NPHASE) STAGE(cur ^ 1, u + 1);
      const char* base = (const char*)&lds[cur][0];
      #pragma unroll
      for (int kk = 0; kk < 2; ++kk) {
        #pragma unroll
        for (int s = 0; s < 4; ++s) {
          const int col = s * 16 + (lane & 15);
          const int kbyte = (kk * 32 + (lane >> 4) * 8) * 2;
          const short8 bfrag =
              *(const short8*)(base + col * 128 + (kbyte ^ ((col & 7) << 4)));
          acc[s] = __builtin_amdgcn_mfma_f32_16x16x32_bf16(
              areg[kb * 2 + kk], bfrag, acc[s], 0, 0, 0);
        }
      }
      cur ^= 1;
    }
    // ---- fused argmax over this 64-column tile ----
    const int colb = colsplit + t * NT;
    #pragma unroll
    for (int s = 0; s < 4; ++s) {
      const int gcol = colb + s * 16 + (lane & 15);
      #pragma unroll
      for (int r = 0; r < 4; ++r) {
        const int grow = rowbase + (lane >> 4) * 4 + r;
        const float dv = acc[s][r];
        if (gcol != grow && dv > rmax[r]) { rmax[r] = dv; ridx[r] = gcol; }
      }
    }
  }

  // ---- cross-lane argmax reduce within each 16-lane group ----
  #pragma unroll
  for (int m = 1; m <= 8; m <<= 1) {
    #pragma unroll
    for (int r = 0; r < 4; ++r) {
      const float om = __shfl_xor(rmax[r], m, 64);
      const int   oi = __shfl_xor(ridx[r], m, 64);
      if (om > rmax[r] || (om == rmax[r] && oi < ridx[r])) {
        rmax[r] = om; ridx[r] = oi;
      }
    }
  }
  if ((lane & 15) == 0) {
    #pragma unroll
    for (int r = 0; r < 4; ++r) {
      const int grow = rowbase + (lane >> 4) * 4 + r;
      pmax[cs * NROWS + grow] = rmax[r];
      pidx[cs * NROWS + grow] = ridx[r];
    }
  }
}

// ---------------- Kernel C1: combine splits, exact f32 distance + log -------
__global__ __launch_bounds__(256) void kdist(const float* __restrict__ in,
                                             const float* __restrict__ inv,
                                             const float* __restrict__ pmax,
                                             const int* __restrict__ pidx,
                                             float* __restrict__ partial) {
  __shared__ float acc4[4];
  const int lane = threadIdx.x & 63;
  const int wave = threadIdx.x >> 6;
  const int row = blockIdx.x * 4 + wave;
  float bm = -3e38f; int bi = 0x7fffffff;
  #pragma unroll
  for (int s = 0; s < CSPLIT; ++s) {
    const float m = pmax[s * NROWS + row];
    const int  ix = pidx[s * NROWS + row];
    if (m > bm || (m == bm && ix < bi)) { bm = m; bi = ix; }
  }
  const float ii = inv[row], jj = inv[bi];
  const float4* pi = (const float4*)(in + (size_t)row * DIM + lane * 8);
  const float4* pj = (const float4*)(in + (size_t)bi * DIM + lane * 8);
  const float4 a0 = pi[0], a1 = pi[1], b0 = pj[0], b1 = pj[1];
  float d, ss = 0.0f;
  d = a0.x*ii - b0.x*jj + 1e-8f; ss += d*d;
  d = a0.y*ii - b0.y*jj + 1e-8f; ss += d*d;
  d = a0.z*ii - b0.z*jj + 1e-8f; ss += d*d;
  d = a0.w*ii - b0.w*jj + 1e-8f; ss += d*d;
  d = a1.x*ii - b1.x*jj + 1e-8f; ss += d*d;
  d = a1.y*ii - b1.y*jj + 1e-8f; ss += d*d;
  d = a1.z*ii - b1.z*jj + 1e-8f; ss += d*d;
  d = a1.w*ii - b1.w*jj + 1e-8f; ss += d*d;
  #pragma unroll
  for (int m = 32; m >= 1; m >>= 1) ss += __shfl_xor(ss, m, 64);
  if (lane == 0) acc4[wave] = logf(sqrtf(ss) + 1e-8f);
  __syncthreads();
  if (threadIdx.x == 0)
    partial[blockIdx.x] = acc4[0] + acc4[1] + acc4[2] + acc4[3];
}

// ---------------- Kernel C2: final reduce -> loss ---------------------------
__global__ __launch_bounds__(256) void kfinal(const float* __restrict__ partial,
                                              float* __restrict__ out) {
  __shared__ float acc4[4];
  const int lane = threadIdx.x & 63;
  const int wave = threadIdx.x >> 6;
  float s = 0.0f;
  for (int i = threadIdx.x; i < NROWS / 4; i += 256) s += partial[i];
  #pragma unroll
  for (int m = 32; m >= 1; m >>= 1) s += __shfl_xor(s, m, 64);
  if (lane == 0) acc4[wave] = s;
  __syncthreads();
  if (threadIdx.x == 0)
    out[0] = -(acc4[0] + acc4[1] + acc4[2] + acc4[3]) * (1.0f / (float)NROWS);
}

extern "C" void kernel_launch(void* const* d_in, const int* in_sizes, int n_in,
                              void* d_out, int out_size, void* d_ws, size_t ws_size,
                              hipStream_t stream) {
  const float* in = (const float*)d_in[0];
  char* ws = (char*)d_ws;
  unsigned short* xb   = (unsigned short*)(ws);                 // 16,777,216 B
  float*          inv  = (float*)(ws + 16777216);               //     65,536 B
  float*          pmax = (float*)(ws + 16842752);               //    524,288 B
  int*            pidx = (int*)  (ws + 17367040);               //    524,288 B
  float*          part = (float*)(ws + 17891328);               //     16,384 B

  knorm<<<NROWS / 4, 256, 0, stream>>>(in, xb, inv);
  kdots<<<(NROWS / BM) * CSPLIT, 256, 0, stream>>>(xb, pmax, pidx);
  kdist<<<NROWS / 4, 256, 0, stream>>>(in, inv, pmax, pidx, part);
  kfinal<<<1, 256, 0, stream>>>(part, (float*)d_out);
}

// Round 2
// 255.095 us; speedup vs baseline: 1.3861x; 1.3861x over previous
//
#include <hip/hip_runtime.h>
#include <stdint.h>

#define NROWS 16384
#define DIM 512
#define CSPLIT 8
#define COLS_PER_SPLIT (NROWS / CSPLIT)   // 2048
#define BM 128                            // rows per block (4 waves x 32)
#define NT 64                             // cols per tile
#define BK 64                             // k per phase
#define NTILES (COLS_PER_SPLIT / NT)      // 32
#define NPHASE (NTILES * 8)               // 256

using short8 = __attribute__((ext_vector_type(8))) short;
using f32x4  = __attribute__((ext_vector_type(4))) float;

#define AS1 __attribute__((address_space(1)))
#define AS3 __attribute__((address_space(3)))

__device__ __forceinline__ unsigned short f2bf(float f) {
  uint32_t u = __float_as_uint(f);
  u += 0x7FFFu + ((u >> 16) & 1u);   // round-to-nearest-even
  return (unsigned short)(u >> 16);
}

// ---------------- Kernel A: row L2-normalize, write bf16 copy + inv-norm ----
__global__ __launch_bounds__(256) void knorm(const float* __restrict__ in,
                                             unsigned short* __restrict__ xb,
                                             float* __restrict__ inv) {
  const int lane = threadIdx.x & 63;
  const int wave = threadIdx.x >> 6;
  const int row = blockIdx.x * 4 + wave;
  const float4* p = (const float4*)(in + (size_t)row * DIM + lane * 8);
  float4 a = p[0], b = p[1];
  float ss = a.x*a.x + a.y*a.y + a.z*a.z + a.w*a.w
           + b.x*b.x + b.y*b.y + b.z*b.z + b.w*b.w;
  #pragma unroll
  for (int m = 32; m >= 1; m >>= 1) ss += __shfl_xor(ss, m, 64);
  const float iv = 1.0f / fmaxf(sqrtf(ss), 1e-8f);
  short8 ov;
  ov[0] = (short)f2bf(a.x * iv); ov[1] = (short)f2bf(a.y * iv);
  ov[2] = (short)f2bf(a.z * iv); ov[3] = (short)f2bf(a.w * iv);
  ov[4] = (short)f2bf(b.x * iv); ov[5] = (short)f2bf(b.y * iv);
  ov[6] = (short)f2bf(b.z * iv); ov[7] = (short)f2bf(b.w * iv);
  *(short8*)(xb + (size_t)row * DIM + lane * 8) = ov;
  if (lane == 0) inv[row] = iv;
}

// ---------------- Kernel B: Gram matrix (x x^T) + fused running argmax ------
// 4 waves x 32 rows each (2 row-frags); A fully register-resident (128 VGPR).
// B col tiles in 4 LDS buffers, depth-3 prefetch via global_load_lds(16B),
// counted s_waitcnt vmcnt(4) + raw s_barrier (never drain to 0 in-loop).
// XOR-swizzled global source so ds_read_b128 fragment reads are conflict-free.
__global__ __launch_bounds__(256, 2) void kdots(const unsigned short* __restrict__ xb,
                                                float* __restrict__ pmax,
                                                int* __restrict__ pidx) {
  const int tid  = threadIdx.x;
  const int lane = tid & 63;
  const int wave = tid >> 6;
  const int bx = blockIdx.x;
  const int cs = bx & (CSPLIT - 1);     // same-cs blocks land on same XCD (%8)
  const int rb = bx >> 3;
  const int rowbase  = rb * BM + wave * 32;
  const int colsplit = cs * COLS_PER_SPLIT;

  __shared__ unsigned short lds[4][NT * BK];   // 4 x 8 KB

  // ---- A fragments in registers: 2 row-frags x 512 k (128 VGPRs) ----
  short8 areg[2][16];
  #pragma unroll
  for (int rf = 0; rf < 2; ++rf) {
    const unsigned short* ap =
        xb + (size_t)(rowbase + rf * 16 + (lane & 15)) * DIM + ((lane >> 4) * 8);
    #pragma unroll
    for (int c = 0; c < 16; ++c)
      areg[rf][c] = *(const short8*)(ap + c * 32);
  }

  float rmax[2][4] = {{-3e38f,-3e38f,-3e38f,-3e38f},{-3e38f,-3e38f,-3e38f,-3e38f}};
  int   ridx[2][4] = {{0,0,0,0},{0,0,0,0}};

  auto STAGE = [&](int buf, int p) {
    const int tt = p >> 3, kb = p & 7;
    const int colbase = colsplit + tt * NT;
    #pragma unroll
    for (int i = 0; i < 2; ++i) {
      const int d = i * 4096 + tid * 16;          // linear dest byte in buffer
      const int col = d >> 7;                     // 128 B per column (64 bf16)
      const int kel = ((tid & 7) ^ (col & 7)) * 8; // pre-swizzled global source
      const unsigned short* g =
          xb + (size_t)(colbase + col) * DIM + kb * BK + kel;
      char* lbase = ((char*)&lds[buf][0]) + i * 4096 + wave * 1024;
      __builtin_amdgcn_global_load_lds((AS1 const void*)g, (AS3 void*)lbase,
                                       16, 0, 0);
    }
  };

  STAGE(0, 0); STAGE(1, 1); STAGE(2, 2);

  for (int t = 0; t < NTILES; ++t) {
    f32x4 acc[2][4] = {{{0,0,0,0},{0,0,0,0},{0,0,0,0},{0,0,0,0}},
                       {{0,0,0,0},{0,0,0,0},{0,0,0,0},{0,0,0,0}}};
    #pragma unroll
    for (int kb = 0; kb < 8; ++kb) {
      // buf for this phase = (t*8+kb)&3 = kb&3 (compile-time per unrolled kb)
      asm volatile("s_waitcnt vmcnt(4)" ::: "memory"); // this buf's loads done
      __builtin_amdgcn_s_barrier();                    // all waves landed/read
      asm volatile("" ::: "memory");
      STAGE((kb + 3) & 3, (t * 8 + kb + 3) & (NPHASE - 1)); // depth-3 prefetch
      const char* base = (const char*)&lds[kb & 3][0];
      __builtin_amdgcn_s_setprio(1);
      #pragma unroll
      for (int kk = 0; kk < 2; ++kk) {
        #pragma unroll
        for (int s = 0; s < 4; ++s) {
          const int col = s * 16 + (lane & 15);
          const int kbyte = kk * 64 + (lane >> 4) * 16;
          const short8 bfrag =
              *(const short8*)(base + col * 128 + (kbyte ^ ((col & 7) << 4)));
          acc[0][s] = __builtin_amdgcn_mfma_f32_16x16x32_bf16(
              areg[0][kb * 2 + kk], bfrag, acc[0][s], 0, 0, 0);
          acc[1][s] = __builtin_amdgcn_mfma_f32_16x16x32_bf16(
              areg[1][kb * 2 + kk], bfrag, acc[1][s], 0, 0, 0);
        }
      }
      __builtin_amdgcn_s_setprio(0);
    }
    // ---- fused argmax over this 64-column tile ----
    const int colb = colsplit + t * NT;
    #pragma unroll
    for (int s = 0; s < 4; ++s) {
      const int gcol = colb + s * 16 + (lane & 15);
      #pragma unroll
      for (int rf = 0; rf < 2; ++rf) {
        #pragma unroll
        for (int r = 0; r < 4; ++r) {
          const int grow = rowbase + rf * 16 + (lane >> 4) * 4 + r;
          const float dv = acc[rf][s][r];
          if (gcol != grow && dv > rmax[rf][r]) { rmax[rf][r] = dv; ridx[rf][r] = gcol; }
        }
      }
    }
  }

  // ---- cross-lane argmax reduce within each 16-lane group ----
  #pragma unroll
  for (int m = 1; m <= 8; m <<= 1) {
    #pragma unroll
    for (int rf = 0; rf < 2; ++rf) {
      #pragma unroll
      for (int r = 0; r < 4; ++r) {
        const float om = __shfl_xor(rmax[rf][r], m, 64);
        const int   oi = __shfl_xor(ridx[rf][r], m, 64);
        if (om > rmax[rf][r] || (om == rmax[rf][r] && oi < ridx[rf][r])) {
          rmax[rf][r] = om; ridx[rf][r] = oi;
        }
      }
    }
  }
  if ((lane & 15) == 0) {
    #pragma unroll
    for (int rf = 0; rf < 2; ++rf) {
      #pragma unroll
      for (int r = 0; r < 4; ++r) {
        const int grow = rowbase + rf * 16 + (lane >> 4) * 4 + r;
        pmax[cs * NROWS + grow] = rmax[rf][r];
        pidx[cs * NROWS + grow] = ridx[rf][r];
      }
    }
  }
}

// ---------------- Kernel C1: combine splits, exact f32 distance + log -------
__global__ __launch_bounds__(256) void kdist(const float* __restrict__ in,
                                             const float* __restrict__ inv,
                                             const float* __restrict__ pmax,
                                             const int* __restrict__ pidx,
                                             float* __restrict__ partial) {
  __shared__ float acc4[4];
  const int lane = threadIdx.x & 63;
  const int wave = threadIdx.x >> 6;
  const int row = blockIdx.x * 4 + wave;
  float bm = -3e38f; int bi = 0x7fffffff;
  #pragma unroll
  for (int s = 0; s < CSPLIT; ++s) {
    const float m = pmax[s * NROWS + row];
    const int  ix = pidx[s * NROWS + row];
    if (m > bm || (m == bm && ix < bi)) { bm = m; bi = ix; }
  }
  const float ii = inv[row], jj = inv[bi];
  const float4* pi = (const float4*)(in + (size_t)row * DIM + lane * 8);
  const float4* pj = (const float4*)(in + (size_t)bi * DIM + lane * 8);
  const float4 a0 = pi[0], a1 = pi[1], b0 = pj[0], b1 = pj[1];
  float d, ss = 0.0f;
  d = a0.x*ii - b0.x*jj + 1e-8f; ss += d*d;
  d = a0.y*ii - b0.y*jj + 1e-8f; ss += d*d;
  d = a0.z*ii - b0.z*jj + 1e-8f; ss += d*d;
  d = a0.w*ii - b0.w*jj + 1e-8f; ss += d*d;
  d = a1.x*ii - b1.x*jj + 1e-8f; ss += d*d;
  d = a1.y*ii - b1.y*jj + 1e-8f; ss += d*d;
  d = a1.z*ii - b1.z*jj + 1e-8f; ss += d*d;
  d = a1.w*ii - b1.w*jj + 1e-8f; ss += d*d;
  #pragma unroll
  for (int m = 32; m >= 1; m >>= 1) ss += __shfl_xor(ss, m, 64);
  if (lane == 0) acc4[wave] = logf(sqrtf(ss) + 1e-8f);
  __syncthreads();
  if (threadIdx.x == 0)
    partial[blockIdx.x] = acc4[0] + acc4[1] + acc4[2] + acc4[3];
}

// ---------------- Kernel C2: final reduce -> loss ---------------------------
__global__ __launch_bounds__(256) void kfinal(const float* __restrict__ partial,
                                              float* __restrict__ out) {
  __shared__ float acc4[4];
  const int lane = threadIdx.x & 63;
  const int wave = threadIdx.x >> 6;
  float s = 0.0f;
  for (int i = threadIdx.x; i < NROWS / 4; i += 256) s += partial[i];
  #pragma unroll
  for (int m = 32; m >= 1; m >>= 1) s += __shfl_xor(s, m, 64);
  if (lane == 0) acc4[wave] = s;
  __syncthreads();
  if (threadIdx.x == 0)
    out[0] = -(acc4[0] + acc4[1] + acc4[2] + acc4[3]) * (1.0f / (float)NROWS);
}

extern "C" void kernel_launch(void* const* d_in, const int* in_sizes, int n_in,
                              void* d_out, int out_size, void* d_ws, size_t ws_size,
                              hipStream_t stream) {
  const float* in = (const float*)d_in[0];
  char* ws = (char*)d_ws;
  unsigned short* xb   = (unsigned short*)(ws);                 // 16,777,216 B
  float*          inv  = (float*)(ws + 16777216);               //     65,536 B
  float*          pmax = (float*)(ws + 16842752);               //    524,288 B
  int*            pidx = (int*)  (ws + 17367040);               //    524,288 B
  float*          part = (float*)(ws + 17891328);               //     16,384 B

  knorm<<<NROWS / 4, 256, 0, stream>>>(in, xb, inv);
  kdots<<<(NROWS / BM) * CSPLIT, 256, 0, stream>>>(xb, pmax, pidx);
  kdist<<<NROWS / 4, 256, 0, stream>>>(in, inv, pmax, pidx, part);
  kfinal<<<1, 256, 0, stream>>>(part, (float*)d_out);
}

// Round 3
// 195.584 us; speedup vs baseline: 1.8079x; 1.3043x over previous
//
#include <hip/hip_runtime.h>
#include <stdint.h>

#define NROWS 16384
#define DIM 512
#define CSPLIT 8
#define COLS_PER_SPLIT (NROWS / CSPLIT)   // 2048
#define BM 256                            // rows per block (4 waves x 64)
#define NT 64                             // cols per tile
#define BK 128                            // k per phase
#define NTILES (COLS_PER_SPLIT / NT)      // 32
#define PPT (DIM / BK)                    // 4 phases per tile
#define NPHASE (NTILES * PPT)             // 128

using i32x4 = __attribute__((ext_vector_type(4))) int;
using char8 = __attribute__((ext_vector_type(8))) signed char;

#define AS1 __attribute__((address_space(1)))
#define AS3 __attribute__((address_space(3)))

// ---------------- Kernel A: L2-normalize + per-row i8 quantize --------------
// q = round(x * 127 / absmax_raw); scale (normalized domain) = absmax_raw*iv/127
__global__ __launch_bounds__(256) void knorm(const float* __restrict__ in,
                                             signed char* __restrict__ xq,
                                             float* __restrict__ inv,
                                             float* __restrict__ scl) {
  const int lane = threadIdx.x & 63;
  const int wave = threadIdx.x >> 6;
  const int row = blockIdx.x * 4 + wave;
  const float4* p = (const float4*)(in + (size_t)row * DIM + lane * 8);
  const float4 a = p[0], b = p[1];
  float ss = a.x*a.x + a.y*a.y + a.z*a.z + a.w*a.w
           + b.x*b.x + b.y*b.y + b.z*b.z + b.w*b.w;
  float am = fmaxf(fmaxf(fmaxf(fabsf(a.x), fabsf(a.y)), fmaxf(fabsf(a.z), fabsf(a.w))),
                   fmaxf(fmaxf(fabsf(b.x), fabsf(b.y)), fmaxf(fabsf(b.z), fabsf(b.w))));
  #pragma unroll
  for (int m = 32; m >= 1; m >>= 1) {
    ss += __shfl_xor(ss, m, 64);
    am = fmaxf(am, __shfl_xor(am, m, 64));
  }
  const float iv = 1.0f / fmaxf(sqrtf(ss), 1e-8f);
  const float r127 = 127.0f / am;
  char8 q;
  q[0] = (signed char)(int)rintf(a.x * r127);
  q[1] = (signed char)(int)rintf(a.y * r127);
  q[2] = (signed char)(int)rintf(a.z * r127);
  q[3] = (signed char)(int)rintf(a.w * r127);
  q[4] = (signed char)(int)rintf(b.x * r127);
  q[5] = (signed char)(int)rintf(b.y * r127);
  q[6] = (signed char)(int)rintf(b.z * r127);
  q[7] = (signed char)(int)rintf(b.w * r127);
  *(char8*)(xq + (size_t)row * DIM + lane * 8) = q;
  if (lane == 0) {
    inv[row] = iv;
    scl[row] = am * iv * (1.0f / 127.0f);
  }
}

// ---------------- Kernel B: i8 Gram + fused running argmax ------------------
// 4 waves x 64 rows (4 rowfrags); A register-resident (128 VGPR as i32x4[4][8]).
// B tiles (64 cols x 128 k, 8 KB) in 4 LDS buffers, depth-3 prefetch via
// global_load_lds(16B) into a [cf][kslot][col][16B] subtile layout so
// ds_read_b128 at lane*16 is linear and conflict-free. Counted vmcnt(4),
// raw s_barrier, setprio around the 32-MFMA cluster. Per-column scales in LDS.
__global__ __launch_bounds__(256, 2) void kdots(const signed char* __restrict__ xq,
                                                const float* __restrict__ scl,
                                                float* __restrict__ pmax,
                                                int* __restrict__ pidx) {
  const int tid  = threadIdx.x;
  const int lane = tid & 63;
  const int wave = tid >> 6;
  const int bx = blockIdx.x;
  const int cs = bx & (CSPLIT - 1);     // same-cs blocks land on same XCD (%8)
  const int rb = bx >> 3;
  const int rowbase  = rb * BM + wave * 64;
  const int colsplit = cs * COLS_PER_SPLIT;

  __shared__ signed char lds[4][NT * BK];   // 4 x 8 KB
  __shared__ float sscl[COLS_PER_SPLIT];    // 8 KB

  // stage this slice's column scales into LDS (read per-tile, lgkm only)
  {
    const float4* sp = (const float4*)(scl + colsplit + tid * 8);
    float4* dp = (float4*)(sscl + tid * 8);
    dp[0] = sp[0];
    dp[1] = sp[1];
  }

  // ---- A fragments in registers: 4 rowfrags x 8 kfrags(K=64) = 128 VGPR ----
  i32x4 areg[4][8];
  #pragma unroll
  for (int rf = 0; rf < 4; ++rf) {
    const signed char* ap =
        xq + (size_t)(rowbase + rf * 16 + (lane & 15)) * DIM + ((lane >> 4) * 16);
    #pragma unroll
    for (int kf = 0; kf < 8; ++kf)
      areg[rf][kf] = *(const i32x4*)(ap + kf * 64);
  }

  float rmax[4][4];
  int   ridx[4][4];
  #pragma unroll
  for (int rf = 0; rf < 4; ++rf)
    #pragma unroll
    for (int r = 0; r < 4; ++r) { rmax[rf][r] = -3e38f; ridx[rf][r] = 0; }

  // subtile staging: LDS linear dest t*16; t -> (cf=t>>7, kslot=(t>>4)&7, c=t&15)
  auto STAGE = [&](int buf, int p) {
    const int tt = p >> 2, kb = p & 3;
    #pragma unroll
    for (int i = 0; i < 2; ++i) {
      const int u = i * 256 + tid;
      const int col = colsplit + tt * NT + ((u >> 7) << 4) + (u & 15);
      const int koff = kb * BK + ((u >> 4) & 7) * 16;
      const signed char* g = xq + (size_t)col * DIM + koff;
      char* l = ((char*)&lds[buf][0]) + i * 4096 + wave * 1024 + (lane * 16);
      __builtin_amdgcn_global_load_lds((AS1 const void*)g, (AS3 void*)l, 16, 0, 0);
    }
  };

  __syncthreads();   // scales visible; drains all prior vmem (vmcnt -> 0)
  STAGE(0, 0); STAGE(1, 1); STAGE(2, 2);   // 6 outstanding

  for (int t = 0; t < NTILES; ++t) {
    i32x4 acc[4][4];
    #pragma unroll
    for (int rf = 0; rf < 4; ++rf)
      #pragma unroll
      for (int cf = 0; cf < 4; ++cf) acc[rf][cf] = (i32x4){0, 0, 0, 0};

    #pragma unroll
    for (int kb = 0; kb < PPT; ++kb) {
      // buffer for this phase = (t*4+kb)&3 = kb&3 (compile-time per unrolled kb)
      asm volatile("s_waitcnt vmcnt(4)" ::: "memory"); // this buf's 2 loads done
      __builtin_amdgcn_s_barrier();
      asm volatile("" ::: "memory");
      STAGE((kb + 3) & 3, (t * PPT + kb + 3) & (NPHASE - 1)); // depth-3 prefetch
      const char* base = (const char*)&lds[kb & 3][0];
      __builtin_amdgcn_s_setprio(1);
      #pragma unroll
      for (int kk = 0; kk < 2; ++kk) {
        #pragma unroll
        for (int cf = 0; cf < 4; ++cf) {
          const i32x4 bf =
              *(const i32x4*)(base + cf * 2048 + kk * 1024 + lane * 16);
          #pragma unroll
          for (int rf = 0; rf < 4; ++rf)
            acc[rf][cf] = __builtin_amdgcn_mfma_i32_16x16x64_i8(
                areg[rf][kb * 2 + kk], bf, acc[rf][cf], 0, 0, 0);
        }
      }
      __builtin_amdgcn_s_setprio(0);
    }

    // ---- fused argmax over this 64-column tile (float rescale per column) --
    const int colb0 = t * NT;
    #pragma unroll
    for (int cf = 0; cf < 4; ++cf) {
      const float sc = sscl[colb0 + cf * 16 + (lane & 15)];
      const int gcol = colsplit + colb0 + cf * 16 + (lane & 15);
      #pragma unroll
      for (int rf = 0; rf < 4; ++rf) {
        #pragma unroll
        for (int r = 0; r < 4; ++r) {
          const int grow = rowbase + rf * 16 + (lane >> 4) * 4 + r;
          const float dv = (float)acc[rf][cf][r] * sc;
          if (gcol != grow && dv > rmax[rf][r]) {
            rmax[rf][r] = dv; ridx[rf][r] = gcol;
          }
        }
      }
    }
  }

  // ---- cross-lane argmax reduce within each 16-lane group --------------
  #pragma unroll
  for (int m = 1; m <= 8; m <<= 1) {
    #pragma unroll
    for (int rf = 0; rf < 4; ++rf) {
      #pragma unroll
      for (int r = 0; r < 4; ++r) {
        const float om = __shfl_xor(rmax[rf][r], m, 64);
        const int   oi = __shfl_xor(ridx[rf][r], m, 64);
        if (om > rmax[rf][r] || (om == rmax[rf][r] && oi < ridx[rf][r])) {
          rmax[rf][r] = om; ridx[rf][r] = oi;
        }
      }
    }
  }
  if ((lane & 15) == 0) {
    #pragma unroll
    for (int rf = 0; rf < 4; ++rf) {
      #pragma unroll
      for (int r = 0; r < 4; ++r) {
        const int grow = rowbase + rf * 16 + (lane >> 4) * 4 + r;
        pmax[cs * NROWS + grow] = rmax[rf][r];
        pidx[cs * NROWS + grow] = ridx[rf][r];
      }
    }
  }
}

// ---------------- Kernel C1: combine splits, exact f32 distance + log -------
__global__ __launch_bounds__(256) void kdist(const float* __restrict__ in,
                                             const float* __restrict__ inv,
                                             const float* __restrict__ pmax,
                                             const int* __restrict__ pidx,
                                             float* __restrict__ partial) {
  __shared__ float acc4[4];
  const int lane = threadIdx.x & 63;
  const int wave = threadIdx.x >> 6;
  const int row = blockIdx.x * 4 + wave;
  float bm = -3e38f; int bi = 0x7fffffff;
  #pragma unroll
  for (int s = 0; s < CSPLIT; ++s) {
    const float m = pmax[s * NROWS + row];
    const int  ix = pidx[s * NROWS + row];
    if (m > bm || (m == bm && ix < bi)) { bm = m; bi = ix; }
  }
  const float ii = inv[row], jj = inv[bi];
  const float4* pi = (const float4*)(in + (size_t)row * DIM + lane * 8);
  const float4* pj = (const float4*)(in + (size_t)bi * DIM + lane * 8);
  const float4 a0 = pi[0], a1 = pi[1], b0 = pj[0], b1 = pj[1];
  float d, ss = 0.0f;
  d = a0.x*ii - b0.x*jj + 1e-8f; ss += d*d;
  d = a0.y*ii - b0.y*jj + 1e-8f; ss += d*d;
  d = a0.z*ii - b0.z*jj + 1e-8f; ss += d*d;
  d = a0.w*ii - b0.w*jj + 1e-8f; ss += d*d;
  d = a1.x*ii - b1.x*jj + 1e-8f; ss += d*d;
  d = a1.y*ii - b1.y*jj + 1e-8f; ss += d*d;
  d = a1.z*ii - b1.z*jj + 1e-8f; ss += d*d;
  d = a1.w*ii - b1.w*jj + 1e-8f; ss += d*d;
  #pragma unroll
  for (int m = 32; m >= 1; m >>= 1) ss += __shfl_xor(ss, m, 64);
  if (lane == 0) acc4[wave] = logf(sqrtf(ss) + 1e-8f);
  __syncthreads();
  if (threadIdx.x == 0)
    partial[blockIdx.x] = acc4[0] + acc4[1] + acc4[2] + acc4[3];
}

// ---------------- Kernel C2: final reduce -> loss ---------------------------
__global__ __launch_bounds__(256) void kfinal(const float* __restrict__ partial,
                                              float* __restrict__ out) {
  __shared__ float acc4[4];
  const int lane = threadIdx.x & 63;
  const int wave = threadIdx.x >> 6;
  float s = 0.0f;
  for (int i = threadIdx.x; i < NROWS / 4; i += 256) s += partial[i];
  #pragma unroll
  for (int m = 32; m >= 1; m >>= 1) s += __shfl_xor(s, m, 64);
  if (lane == 0) acc4[wave] = s;
  __syncthreads();
  if (threadIdx.x == 0)
    out[0] = -(acc4[0] + acc4[1] + acc4[2] + acc4[3]) * (1.0f / (float)NROWS);
}

extern "C" void kernel_launch(void* const* d_in, const int* in_sizes, int n_in,
                              void* d_out, int out_size, void* d_ws, size_t ws_size,
                              hipStream_t stream) {
  const float* in = (const float*)d_in[0];
  char* ws = (char*)d_ws;
  signed char* xq   = (signed char*)(ws);                  //  8,388,608 B
  float*       inv  = (float*)(ws + 8388608);              //     65,536 B
  float*       scl  = (float*)(ws + 8454144);              //     65,536 B
  float*       pmax = (float*)(ws + 8519680);              //    524,288 B
  int*         pidx = (int*)  (ws + 9043968);              //    524,288 B
  float*       part = (float*)(ws + 9568256);              //     16,384 B

  knorm<<<NROWS / 4, 256, 0, stream>>>(in, xq, inv, scl);
  kdots<<<(NROWS / BM) * CSPLIT, 256, 0, stream>>>(xq, scl, pmax, pidx);
  kdist<<<NROWS / 4, 256, 0, stream>>>(in, inv, pmax, pidx, part);
  kfinal<<<1, 256, 0, stream>>>(part, (float*)d_out);
}

// Round 4
// 175.200 us; speedup vs baseline: 2.0182x; 1.1163x over previous
//
#include <hip/hip_runtime.h>
#include <stdint.h>

#define NROWS 16384
#define DIM 512
#define CSPLIT 8
#define COLS_PER_SPLIT (NROWS / CSPLIT)   // 2048
#define BM 256                            // rows per block (4 waves x 64)
#define NT 64                             // cols per tile
#define BK 128                            // k per phase
#define NTILES (COLS_PER_SPLIT / NT)      // 32
#define PPT (DIM / BK)                    // 4 phases per tile
#define NPHASE (NTILES * PPT)             // 128

using i32x4 = __attribute__((ext_vector_type(4))) int;
using char8 = __attribute__((ext_vector_type(8))) signed char;

#define AS1 __attribute__((address_space(1)))
#define AS3 __attribute__((address_space(3)))

// ---------------- Kernel A: L2-normalize + per-row i8 quantize --------------
__global__ __launch_bounds__(256) void knorm(const float* __restrict__ in,
                                             signed char* __restrict__ xq,
                                             float* __restrict__ inv,
                                             float* __restrict__ scl) {
  const int lane = threadIdx.x & 63;
  const int wave = threadIdx.x >> 6;
  const int row = blockIdx.x * 4 + wave;
  const float4* p = (const float4*)(in + (size_t)row * DIM + lane * 8);
  const float4 a = p[0], b = p[1];
  float ss = a.x*a.x + a.y*a.y + a.z*a.z + a.w*a.w
           + b.x*b.x + b.y*b.y + b.z*b.z + b.w*b.w;
  float am = fmaxf(fmaxf(fmaxf(fabsf(a.x), fabsf(a.y)), fmaxf(fabsf(a.z), fabsf(a.w))),
                   fmaxf(fmaxf(fabsf(b.x), fabsf(b.y)), fmaxf(fabsf(b.z), fabsf(b.w))));
  #pragma unroll
  for (int m = 32; m >= 1; m >>= 1) {
    ss += __shfl_xor(ss, m, 64);
    am = fmaxf(am, __shfl_xor(am, m, 64));
  }
  const float iv = 1.0f / fmaxf(sqrtf(ss), 1e-8f);
  const float r127 = 127.0f / am;
  char8 q;
  q[0] = (signed char)(int)rintf(a.x * r127);
  q[1] = (signed char)(int)rintf(a.y * r127);
  q[2] = (signed char)(int)rintf(a.z * r127);
  q[3] = (signed char)(int)rintf(a.w * r127);
  q[4] = (signed char)(int)rintf(b.x * r127);
  q[5] = (signed char)(int)rintf(b.y * r127);
  q[6] = (signed char)(int)rintf(b.z * r127);
  q[7] = (signed char)(int)rintf(b.w * r127);
  *(char8*)(xq + (size_t)row * DIM + lane * 8) = q;
  if (lane == 0) {
    inv[row] = iv;
    scl[row] = am * iv * (1.0f / 127.0f);
  }
}

// ---------------- Kernel B: i8 Gram + fused running argmax ------------------
// 4 waves x 64 rows (4 rowfrags); A register-resident. B tiles (64c x 128k,
// 8 KB) in 4 LDS buffers, depth-3 prefetch, counted vmcnt(4) once per K-step.
// K-step split into 4 sub-phases (one per cf): {2 ds_read + stage-half ->
// barrier -> lgkmcnt(0) -> sched_barrier -> setprio(1) 8xMFMA setprio(0) ->
// barrier} — the m201-style fine interleave that creates wave role-split.
__global__ __launch_bounds__(256, 2) void kdots(const signed char* __restrict__ xq,
                                                const float* __restrict__ scl,
                                                float* __restrict__ pmax,
                                                int* __restrict__ pidx) {
  const int tid  = threadIdx.x;
  const int lane = tid & 63;
  const int wave = tid >> 6;
  const int bx = blockIdx.x;
  const int cs = bx & (CSPLIT - 1);     // same-cs blocks land on same XCD (%8)
  const int rb = bx >> 3;
  const int rowbase  = rb * BM + wave * 64;
  const int colsplit = cs * COLS_PER_SPLIT;

  __shared__ signed char lds[4][NT * BK];   // 4 x 8 KB
  __shared__ float sscl[COLS_PER_SPLIT];    // 8 KB

  // stage this slice's column scales into LDS (written once, read in epilogue)
  {
    const float4* sp = (const float4*)(scl + colsplit + tid * 8);
    float4* dp = (float4*)(sscl + tid * 8);
    dp[0] = sp[0];
    dp[1] = sp[1];
  }

  // ---- A fragments in registers: 4 rowfrags x 8 kfrags(K=64) = 128 VGPR ----
  i32x4 areg[4][8];
  #pragma unroll
  for (int rf = 0; rf < 4; ++rf) {
    const signed char* ap =
        xq + (size_t)(rowbase + rf * 16 + (lane & 15)) * DIM + ((lane >> 4) * 16);
    #pragma unroll
    for (int kf = 0; kf < 8; ++kf)
      areg[rf][kf] = *(const i32x4*)(ap + kf * 64);
  }

  float rmax[4][4];
  int   ridx[4][4];
  #pragma unroll
  for (int rf = 0; rf < 4; ++rf)
    #pragma unroll
    for (int r = 0; r < 4; ++r) { rmax[rf][r] = -3e38f; ridx[rf][r] = 0; }

  // stage one 4 KB half of a buffer: 1 global_load_lds(16B) per thread
  auto STAGE_HALF = [&](int buf, int p, int half) {
    const int tt = p >> 2, kb2 = p & 3;
    const int u = half * 256 + tid;
    const int col = colsplit + tt * NT + ((u >> 7) << 4) + (u & 15);
    const int koff = kb2 * BK + ((u >> 4) & 7) * 16;
    const signed char* g = xq + (size_t)col * DIM + koff;
    char* l = ((char*)&lds[buf][0]) + u * 16;
    __builtin_amdgcn_global_load_lds((AS1 const void*)g, (AS3 void*)l, 16, 0, 0);
  };

  __syncthreads();   // scales visible; drains all prior vmem (vmcnt -> 0)
  #pragma unroll
  for (int pp = 0; pp < 3; ++pp) {       // prologue: 6 outstanding
    STAGE_HALF(pp, pp, 0);
    STAGE_HALF(pp, pp, 1);
  }

  for (int t = 0; t < NTILES; ++t) {
    i32x4 acc[4][4];
    #pragma unroll
    for (int rf = 0; rf < 4; ++rf)
      #pragma unroll
      for (int cf = 0; cf < 4; ++cf) acc[rf][cf] = (i32x4){0, 0, 0, 0};

    #pragma unroll
    for (int kb = 0; kb < PPT; ++kb) {
      // buffer for this K-step = (t*4+kb)&3 = kb&3 (compile-time per kb)
      asm volatile("s_waitcnt vmcnt(4)" ::: "memory"); // this buf's 2 halves in
      __builtin_amdgcn_s_barrier();                    // ...in ALL waves
      asm volatile("" ::: "memory");
      const char* base = (const char*)&lds[kb & 3][0];
      const int pn = (t * PPT + kb + 3) & (NPHASE - 1); // depth-3 prefetch
      #pragma unroll
      for (int q = 0; q < 4; ++q) {                    // sub-phase = one cf
        const i32x4 bf0 = *(const i32x4*)(base + q * 2048 + lane * 16);
        const i32x4 bf1 = *(const i32x4*)(base + q * 2048 + 1024 + lane * 16);
        if (q < 2) STAGE_HALF((kb + 3) & 3, pn, q);
        __builtin_amdgcn_s_barrier();
        asm volatile("s_waitcnt lgkmcnt(0)" ::: "memory");
        __builtin_amdgcn_sched_barrier(0);
        __builtin_amdgcn_s_setprio(1);
        #pragma unroll
        for (int rf = 0; rf < 4; ++rf)
          acc[rf][q] = __builtin_amdgcn_mfma_i32_16x16x64_i8(
              areg[rf][kb * 2 + 0], bf0, acc[rf][q], 0, 0, 0);
        #pragma unroll
        for (int rf = 0; rf < 4; ++rf)
          acc[rf][q] = __builtin_amdgcn_mfma_i32_16x16x64_i8(
              areg[rf][kb * 2 + 1], bf1, acc[rf][q], 0, 0, 0);
        __builtin_amdgcn_s_setprio(0);
        __builtin_amdgcn_s_barrier();
        asm volatile("" ::: "memory");
      }
    }

    // ---- fused argmax over this 64-column tile (float rescale per column) --
    const int colb0 = t * NT;
    #pragma unroll
    for (int cf = 0; cf < 4; ++cf) {
      const float sc = sscl[colb0 + cf * 16 + (lane & 15)];
      const int gcol = colsplit + colb0 + cf * 16 + (lane & 15);
      #pragma unroll
      for (int rf = 0; rf < 4; ++rf) {
        #pragma unroll
        for (int r = 0; r < 4; ++r) {
          const int grow = rowbase + rf * 16 + (lane >> 4) * 4 + r;
          const float dv = (float)acc[rf][cf][r] * sc;
          if (gcol != grow && dv > rmax[rf][r]) {
            rmax[rf][r] = dv; ridx[rf][r] = gcol;
          }
        }
      }
    }
  }

  // ---- cross-lane argmax reduce within each 16-lane group --------------
  #pragma unroll
  for (int m = 1; m <= 8; m <<= 1) {
    #pragma unroll
    for (int rf = 0; rf < 4; ++rf) {
      #pragma unroll
      for (int r = 0; r < 4; ++r) {
        const float om = __shfl_xor(rmax[rf][r], m, 64);
        const int   oi = __shfl_xor(ridx[rf][r], m, 64);
        if (om > rmax[rf][r] || (om == rmax[rf][r] && oi < ridx[rf][r])) {
          rmax[rf][r] = om; ridx[rf][r] = oi;
        }
      }
    }
  }
  if ((lane & 15) == 0) {
    #pragma unroll
    for (int rf = 0; rf < 4; ++rf) {
      #pragma unroll
      for (int r = 0; r < 4; ++r) {
        const int grow = rowbase + rf * 16 + (lane >> 4) * 4 + r;
        pmax[cs * NROWS + grow] = rmax[rf][r];
        pidx[cs * NROWS + grow] = ridx[rf][r];
      }
    }
  }
}

// ---------------- Kernel C1: combine splits, exact f32 distance + log -------
__global__ __launch_bounds__(256) void kdist(const float* __restrict__ in,
                                             const float* __restrict__ inv,
                                             const float* __restrict__ pmax,
                                             const int* __restrict__ pidx,
                                             float* __restrict__ partial) {
  __shared__ float acc4[4];
  const int lane = threadIdx.x & 63;
  const int wave = threadIdx.x >> 6;
  const int row = blockIdx.x * 4 + wave;
  float bm = -3e38f; int bi = 0x7fffffff;
  #pragma unroll
  for (int s = 0; s < CSPLIT; ++s) {
    const float m = pmax[s * NROWS + row];
    const int  ix = pidx[s * NROWS + row];
    if (m > bm || (m == bm && ix < bi)) { bm = m; bi = ix; }
  }
  const float ii = inv[row], jj = inv[bi];
  const float4* pi = (const float4*)(in + (size_t)row * DIM + lane * 8);
  const float4* pj = (const float4*)(in + (size_t)bi * DIM + lane * 8);
  const float4 a0 = pi[0], a1 = pi[1], b0 = pj[0], b1 = pj[1];
  float d, ss = 0.0f;
  d = a0.x*ii - b0.x*jj + 1e-8f; ss += d*d;
  d = a0.y*ii - b0.y*jj + 1e-8f; ss += d*d;
  d = a0.z*ii - b0.z*jj + 1e-8f; ss += d*d;
  d = a0.w*ii - b0.w*jj + 1e-8f; ss += d*d;
  d = a1.x*ii - b1.x*jj + 1e-8f; ss += d*d;
  d = a1.y*ii - b1.y*jj + 1e-8f; ss += d*d;
  d = a1.z*ii - b1.z*jj + 1e-8f; ss += d*d;
  d = a1.w*ii - b1.w*jj + 1e-8f; ss += d*d;
  #pragma unroll
  for (int m = 32; m >= 1; m >>= 1) ss += __shfl_xor(ss, m, 64);
  if (lane == 0) acc4[wave] = logf(sqrtf(ss) + 1e-8f);
  __syncthreads();
  if (threadIdx.x == 0)
    partial[blockIdx.x] = acc4[0] + acc4[1] + acc4[2] + acc4[3];
}

// ---------------- Kernel C2: final reduce -> loss ---------------------------
__global__ __launch_bounds__(256) void kfinal(const float* __restrict__ partial,
                                              float* __restrict__ out) {
  __shared__ float acc4[4];
  const int lane = threadIdx.x & 63;
  const int wave = threadIdx.x >> 6;
  float s = 0.0f;
  for (int i = threadIdx.x; i < NROWS / 4; i += 256) s += partial[i];
  #pragma unroll
  for (int m = 32; m >= 1; m >>= 1) s += __shfl_xor(s, m, 64);
  if (lane == 0) acc4[wave] = s;
  __syncthreads();
  if (threadIdx.x == 0)
    out[0] = -(acc4[0] + acc4[1] + acc4[2] + acc4[3]) * (1.0f / (float)NROWS);
}

extern "C" void kernel_launch(void* const* d_in, const int* in_sizes, int n_in,
                              void* d_out, int out_size, void* d_ws, size_t ws_size,
                              hipStream_t stream) {
  const float* in = (const float*)d_in[0];
  char* ws = (char*)d_ws;
  signed char* xq   = (signed char*)(ws);                  //  8,388,608 B
  float*       inv  = (float*)(ws + 8388608);              //     65,536 B
  float*       scl  = (float*)(ws + 8454144);              //     65,536 B
  float*       pmax = (float*)(ws + 8519680);              //    524,288 B
  int*         pidx = (int*)  (ws + 9043968);              //    524,288 B
  float*       part = (float*)(ws + 9568256);              //     16,384 B

  knorm<<<NROWS / 4, 256, 0, stream>>>(in, xq, inv, scl);
  kdots<<<(NROWS / BM) * CSPLIT, 256, 0, stream>>>(xq, scl, pmax, pidx);
  kdist<<<NROWS / 4, 256, 0, stream>>>(in, inv, pmax, pidx, part);
  kfinal<<<1, 256, 0, stream>>>(part, (float*)d_out);
}